// Round 3
// baseline (116.062 us; speedup 1.0000x reference)
//
#include <hip/hip_runtime.h>

// FConv2d exact reduced form (fp32 in/out):
// out[b, d*16+n, r, s] =
//   0.5 * sum_{c2<32,u,v<3} W[n,c2,2-u,2-v] * (xa + xb)[r+u, s+v]
// xa = x[b,(8d-c2)%128], xb = x[b,(-8d-c2)%128], zero outside 32x32.
//
// Derivation: rfftn(ch,h,w) -> pointwise mul -> irfftn(h,w) is a spatial
// circular conv per channel-frequency kc; contracting kc with
// cos(2*pi*8d*kc/128)/128 (wn einsum + .real) is the symmetrized inverse
// channel-DFT at position 8d. The irfft Hermitian-extension corrections
// cancel exactly under the cos (kc <-> -kc symmetric) weighting, because
// the symmetrized spectrum IS Hermitian. PAD=2 slicing kills all spatial
// wraparound, leaving a forward 3x3 correlation with flipped weights.

#define NT 256

__global__ __launch_bounds__(NT, 2)
void fconv_kernel(const float* __restrict__ x,
                  const float* __restrict__ wgt,
                  float* __restrict__ out) {
    __shared__ float xs[32 * 10 * 36];   // 46080 B, [c2][rr][w] stride 36 (16B-aligned rows)
    __shared__ float wf[288 * 16];       // 18432 B, [(c2*9+u*3+v)][n]   total 64512 B

    const int rq = blockIdx.x;      // 0..3   8-row band
    const int d  = blockIdx.y;      // 0..15
    const int b  = blockIdx.z;      // 0..15
    const int t  = threadIdx.x;
    const int h0 = rq * 8;

    // ---- flipped weights: wf[c2*9+u*3+v][n] = W[n][c2][2-u][2-v] ----
    for (int k = t; k < 288 * 16; k += NT) {
        const int n = k & 15, m = k >> 4;
        const int c2 = m / 9, r = m - c2 * 9, u = r / 3, v = r - u * 3;
        wf[k] = wgt[((n * 32 + c2) * 3 + (2 - u)) * 3 + (2 - v)];
    }

    // ---- stage combined channel rows: 0.5*(xa+xb), zero-padded ----
    for (int task = t; task < 320; task += NT) {
        const int c2 = task / 10, rr = task - c2 * 10;
        const int g = h0 + rr;
        float* row = &xs[(c2 * 10 + rr) * 36];
        if (g < 32) {
            const int c1a = (8 * d - c2 + 128) & 127;
            const int c1b = (256 - 8 * d - c2) & 127;
            const float4* pa = (const float4*)(x + (((b * 128 + c1a) * 32 + g) << 5));
            const float4* pb = (const float4*)(x + (((b * 128 + c1b) * 32 + g) << 5));
#pragma unroll
            for (int i = 0; i < 8; ++i) {
                const float4 A = pa[i], B = pb[i];
                row[4 * i + 0] = 0.5f * (A.x + B.x);
                row[4 * i + 1] = 0.5f * (A.y + B.y);
                row[4 * i + 2] = 0.5f * (A.z + B.z);
                row[4 * i + 3] = 0.5f * (A.w + B.w);
            }
        } else {
#pragma unroll
            for (int i = 0; i < 32; ++i) row[i] = 0.f;
        }
        row[32] = 0.f; row[33] = 0.f; row[34] = 0.f; row[35] = 0.f;
    }
    __syncthreads();

    // ---- compute: thread = (n, row-in-band, col-half) ----
    const int n  = t & 15;
    const int q  = t >> 4;
    const int rl = q >> 1;          // 0..7
    const int w0 = (q & 1) << 4;    // 0 or 16

    float acc[16];
#pragma unroll
    for (int w = 0; w < 16; ++w) acc[w] = 0.f;

    for (int c2 = 0; c2 < 32; ++c2) {
        float wt[9];
#pragma unroll
        for (int k = 0; k < 9; ++k) wt[k] = wf[(c2 * 9 + k) * 16 + n];

#pragma unroll
        for (int u = 0; u < 3; ++u) {
            const float* p = &xs[(c2 * 10 + rl + u) * 36 + w0];  // 16B-aligned
            float rv[18];
            *reinterpret_cast<float4*>(rv)      = *reinterpret_cast<const float4*>(p);
            *reinterpret_cast<float4*>(rv + 4)  = *reinterpret_cast<const float4*>(p + 4);
            *reinterpret_cast<float4*>(rv + 8)  = *reinterpret_cast<const float4*>(p + 8);
            *reinterpret_cast<float4*>(rv + 12) = *reinterpret_cast<const float4*>(p + 12);
            *reinterpret_cast<float2*>(rv + 16) = *reinterpret_cast<const float2*>(p + 16);
#pragma unroll
            for (int w = 0; w < 16; ++w)
                acc[w] += wt[u * 3 + 0] * rv[w]
                        + wt[u * 3 + 1] * rv[w + 1]
                        + wt[u * 3 + 2] * rv[w + 2];
        }
    }

    float* op = out + ((size_t)((b * 256 + d * 16 + n) * 32 + (h0 + rl)) << 5) + w0;
#pragma unroll
    for (int i = 0; i < 4; ++i)
        *reinterpret_cast<float4*>(op + 4 * i) = *reinterpret_cast<float4*>(acc + 4 * i);
}

extern "C" void kernel_launch(void* const* d_in, const int* in_sizes, int n_in,
                              void* d_out, int out_size, void* d_ws, size_t ws_size,
                              hipStream_t stream) {
    const float* x   = (const float*)d_in[0];   // (16,128,32,32) fp32
    const float* wgt = (const float*)d_in[1];   // (16,32,3,3)   fp32
    float* out = (float*)d_out;                 // (16,256,32,32) fp32
    (void)in_sizes; (void)n_in; (void)out_size; (void)d_ws; (void)ws_size;

    dim3 grid(4, 16, 16);   // (row-band, d, b)
    dim3 block(NT);
    fconv_kernel<<<grid, block, 0, stream>>>(x, wgt, out);
}

// Round 4
// 79.124 us; speedup vs baseline: 1.4668x; 1.4668x over previous
//
#include <hip/hip_runtime.h>
#include <hip/hip_bf16.h>

// FConv2d exact reduced form:
// out[b, d*16+n, r, s] =
//   0.5 * sum_{c2<32,u,v<3} W[n,c2,2-u,2-v] * (xa + xb)[r+u, s+v]
// xa = x[b,(8d-c2)%128], xb = x[b,(-8d-c2)%128], zero outside 32x32.
// (FFT pipeline == symmetrized inverse channel-DFT + 3x3 correlation; verified
//  exact in fp32 in round 3, absmax 7.8e-3 vs np ref.)
//
// MFMA formulation: per (b,d): out[16 n x 1024 pos] = Wflip[16 x 288] @ patch[288 x 1024]
// K-step = one tap (u,v) x 32 c2. xcomb staged in LDS as [c2_octet][r][s][8 c2] bf16
// so each B-fragment lane (col=lane&15, k=quad*8+j) is ONE ds_read_b128.
// A (weights) entirely in registers: af[9] = 8 bf16/lane per tap.
// Block = (b, d, 16-row half-band): 512 threads = 8 waves, 4 (16x16) tiles each.

typedef __attribute__((ext_vector_type(8))) short short8;
typedef __attribute__((ext_vector_type(4))) short short4v;
typedef __attribute__((ext_vector_type(4))) float floatx4;

#define NT 512

static __device__ __forceinline__ short bf16bits(float f) {
    __hip_bfloat16 h = __float2bfloat16(f);
    return __builtin_bit_cast(short, h);
}

__global__ __launch_bounds__(NT, 4)
void fconv_mfma(const float* __restrict__ x,
                const float* __restrict__ wgt,
                float* __restrict__ out) {
    // xs[q][r][s][j]: q = c2 octet (4), r = input row 0..17, s = col 0..33, j = c2 in octet
    __shared__ short xs[4 * 18 * 34 * 8];   // 39168 B

    const int half = blockIdx.x;    // 0..1 : 16-row half band
    const int d    = blockIdx.y;    // 0..15
    const int b    = blockIdx.z;    // 0..15
    const int r0   = half * 16;
    const int tid  = threadIdx.x;

    // ---- stage xcomb = 0.5*(xa+xb) as bf16, layout [q][r][s][8] ----
    // task = (c2 quad, input row, s quad): 8 * 18 * 8 = 1152 tasks
#pragma unroll
    for (int it = 0; it < 3; ++it) {
        const int task = tid + it * NT;
        if (task < 1152) {
            const int c2q = task / 144;           // 0..7 (4 c2 each)
            const int rem = task - c2q * 144;
            const int r   = rem >> 3;             // 0..17
            const int sq  = rem & 7;              // 0..7 (4 s each)
            const int gr  = r0 + r;
            short vals[4][4];                     // [cc][ss]
            if (gr < 32) {
#pragma unroll
                for (int cc = 0; cc < 4; ++cc) {
                    const int c2  = c2q * 4 + cc;
                    const int c1a = (8 * d - c2) & 127;
                    const int c1b = (-8 * d - c2) & 127;
                    const float4 A = *(const float4*)(x + (size_t)((b * 128 + c1a) * 1024 + gr * 32 + sq * 4));
                    const float4 B = *(const float4*)(x + (size_t)((b * 128 + c1b) * 1024 + gr * 32 + sq * 4));
                    vals[cc][0] = bf16bits(0.5f * (A.x + B.x));
                    vals[cc][1] = bf16bits(0.5f * (A.y + B.y));
                    vals[cc][2] = bf16bits(0.5f * (A.z + B.z));
                    vals[cc][3] = bf16bits(0.5f * (A.w + B.w));
                }
            } else {
#pragma unroll
                for (int cc = 0; cc < 4; ++cc)
#pragma unroll
                    for (int ss = 0; ss < 4; ++ss) vals[cc][ss] = 0;
            }
            const int octet = c2q >> 1;
            const int hb    = (c2q & 1) * 4;
#pragma unroll
            for (int ss = 0; ss < 4; ++ss) {
                const int s = sq * 4 + ss;
                short4v p;
                p.x = vals[0][ss]; p.y = vals[1][ss];
                p.z = vals[2][ss]; p.w = vals[3][ss];
                *(short4v*)&xs[(((octet * 18 + r) * 34 + s) << 3) + hb] = p;
            }
        }
    }
    // s-apron (s = 32,33) zeros: 18 r * 2 s * 4 octets, one b128 each
    if (tid < 144) {
        const int r  = tid >> 3;
        const int k  = tid & 7;
        const int s  = 32 + (k >> 2);
        const int oc = k & 3;
        short8 z = {0, 0, 0, 0, 0, 0, 0, 0};
        *(short8*)&xs[((oc * 18 + r) * 34 + s) << 3] = z;
    }

    // ---- A fragments (flipped weights) in registers ----
    const int lane = tid & 63;
    const int c    = lane & 15;     // A: m=n index; B: col; D: col
    const int q    = lane >> 4;     // k-octet select; D: row group
    short8 af[9];
#pragma unroll
    for (int u = 0; u < 3; ++u)
#pragma unroll
        for (int v = 0; v < 3; ++v) {
            short8 f;
#pragma unroll
            for (int j = 0; j < 8; ++j) {
                const int c2 = q * 8 + j;
                f[j] = bf16bits(wgt[((c * 32 + c2) * 3 + (2 - u)) * 3 + (2 - v)]);
            }
            af[u * 3 + v] = f;
        }

    __syncthreads();

    // ---- compute: wave w does 4 tiles (2 rows x 2 col-halves) ----
    const int w = tid >> 6;
#pragma unroll
    for (int i = 0; i < 4; ++i) {
        const int lr = 2 * w + (i >> 1);      // local output row 0..15
        const int s0 = (i & 1) << 4;          // 0 or 16
        floatx4 acc = {0.f, 0.f, 0.f, 0.f};
        const short* basep = &xs[((q * 18 + lr) * 34 + (s0 + c)) << 3];
#pragma unroll
        for (int u = 0; u < 3; ++u)
#pragma unroll
            for (int v = 0; v < 3; ++v) {
                const short8 bf = *(const short8*)(basep + ((u * 34 + v) << 3));
                acc = __builtin_amdgcn_mfma_f32_16x16x32_bf16(af[u * 3 + v], bf, acc, 0, 0, 0);
            }
        // D: col = c (s = s0+c), row = q*4+reg (n)
        float* op = out + (size_t)(((b * 256 + d * 16 + q * 4) * 32 + (r0 + lr)) * 32 + s0 + c);
        op[0]    = acc.x;
        op[1024] = acc.y;
        op[2048] = acc.z;
        op[3072] = acc.w;
    }
}

extern "C" void kernel_launch(void* const* d_in, const int* in_sizes, int n_in,
                              void* d_out, int out_size, void* d_ws, size_t ws_size,
                              hipStream_t stream) {
    const float* x   = (const float*)d_in[0];   // (16,128,32,32) fp32
    const float* wgt = (const float*)d_in[1];   // (16,32,3,3)   fp32
    float* out = (float*)d_out;                 // (16,256,32,32) fp32
    (void)in_sizes; (void)n_in; (void)out_size; (void)d_ws; (void)ws_size;

    dim3 grid(2, 16, 16);   // (half-band, d, b)
    dim3 block(NT);
    fconv_mfma<<<grid, block, 0, stream>>>(x, wgt, out);
}